// Round 3
// baseline (64293.512 us; speedup 1.0000x reference)
//
#include <hip/hip_runtime.h>
#include <math.h>

// ---------------------------------------------------------------------------
// FastFFTNet autoregressive sampler on MI355X — XCD-local pipeline, round 2.
// Cross-block comms: workgroup-scope atomic CAS reads (always execute in the
// local XCD L2, never L1) + plain write-through stores + vmcnt drains.
// Arithmetic is bit-identical to the round-0 kernel that matched numpy exactly.
//
// Roles: 0 sampler | 1 L0 (full Wo_0, idx->x1) | 2..11 A_j (j=role-1)
//        12..21 B_j (j=role-11) | 22..31 helper_j (j=role-21, past taps)
// ---------------------------------------------------------------------------

#define T_STEPS 2048
#define NROLE   32
#define NBLK    256

// ws float offsets
#define OFF_EMBT   0           // tanh(emb_raw)            [256][256]
#define OFF_WPET   65536       // WV_present[0] @ emb^T    [class][256]
#define OFF_WVPET  131072      // WV_past[0]    @ emb^T    [class][256]
#define OFF_RINGS  196608      // ring_j at +512*((1<<j)-1), 512<<j floats
#define OFF_TAPS   1244672     // [10][16][256]
#define OFF_Z      1285632     // [11][2][256]; slot (0,0) doubles as x1
#define WS_FLOATS  1291520

// flag ints (padded to 32 ints each)
#define FZ(j,s)  ((((j)*2)+(s))*32)     // 0..671
#define FTAP(j)  ((21+(j))*32)          // 704..992
#define FIDX     (32*32)                // 1024
#define FBAR(r)  ((40+(r))*32)          // 1280.. (agent-scope only)
#define NZERO_INTS 1280
#define CHOSEN   2432
#define TICKET   2464

#define XCC_GETREG ((31 << 11) | 20)    // hwreg(HW_REG_XCC_ID, 0, 32)

// ---- agent-scope prims (init phase only; proven in round 0) ---------------
__device__ __forceinline__ void stc(float* p, float x) {
  __hip_atomic_store((int*)p, __float_as_int(x), __ATOMIC_RELAXED, __HIP_MEMORY_SCOPE_AGENT);
}
__device__ __forceinline__ void wait1(int* f, int want) {
  int it = 0;
  while (__hip_atomic_load(f, __ATOMIC_RELAXED, __HIP_MEMORY_SCOPE_AGENT) < want) {
    if (++it > (1 << 22)) break;
  }
  (void)__hip_atomic_load(f, __ATOMIC_ACQUIRE, __HIP_MEMORY_SCOPE_AGENT);
}
__device__ __forceinline__ void post(int* f, int v) {
  __hip_atomic_store(f, v, __ATOMIC_RELEASE, __HIP_MEMORY_SCOPE_AGENT);
}

// ---- XCD-L2 prims: CAS with impossible compare == L1-bypassing L2 read ----
#define SENT  0x7fffffff
#define SENT2 0x7ffffffe
__device__ __forceinline__ int ld_i32_l2(int* p) {
  int e = SENT;
  __hip_atomic_compare_exchange_strong(p, &e, SENT2, __ATOMIC_RELAXED,
                                       __ATOMIC_RELAXED, __HIP_MEMORY_SCOPE_WORKGROUP);
  return e;
}
__device__ __forceinline__ float ld_f32_l2(float* p) {
  int e = SENT;
  __hip_atomic_compare_exchange_strong((int*)p, &e, SENT2, __ATOMIC_RELAXED,
                                       __ATOMIC_RELAXED, __HIP_MEMORY_SCOPE_WORKGROUP);
  return __int_as_float(e);
}
__device__ __forceinline__ int wait_l2(int* f, int want, int& budget) {
  int v;
  do { v = ld_i32_l2(f); } while (v < want && --budget > 0);
  return v;
}
__device__ __forceinline__ void drain() { asm volatile("s_waitcnt vmcnt(0)" ::: "memory"); }

__global__ __launch_bounds__(512, 2)
void fftnet_kernel(const float* __restrict__ y, const float* __restrict__ samples,
                   const float* __restrict__ emb_raw, const float* __restrict__ condW,
                   const float* __restrict__ WV_past, const float* __restrict__ WV_present,
                   const float* __restrict__ W_o_w, const float* __restrict__ W_o_b,
                   const float* __restrict__ end_w, const float* __restrict__ end_b,
                   int* __restrict__ out, float* __restrict__ ws)
{
  const int tid = threadIdx.x;
  int* iflags = (int*)(ws + WS_FLOATS);

  __shared__ float s_x[256];
  __shared__ float s_h[256];
  __shared__ float s_p[1024];
  __shared__ float s_cond[16 * 256];
  __shared__ float s_m[320];
  __shared__ unsigned long long s_mask[8];
  __shared__ int s_i[2];

  // ---- role assignment ----------------------------------------------------
  if (blockIdx.x == 0) {
    // zero pipeline flags with PLAIN stores -> writes through THIS (chosen)
    // XCD's L2, overwriting any stale lines from a previous launch.
    for (int i = tid; i < NZERO_INTS; i += 512) iflags[i] = 0;
    drain();
    if (tid == 0)
      __hip_atomic_store(iflags + TICKET, 0, __ATOMIC_RELAXED, __HIP_MEMORY_SCOPE_AGENT);
    __threadfence();
    __syncthreads();
    if (tid == 0) {
      int xcc = __builtin_amdgcn_s_getreg(XCC_GETREG) & 15;
      __hip_atomic_store(iflags + CHOSEN, xcc + 1, __ATOMIC_RELEASE, __HIP_MEMORY_SCOPE_AGENT);
    }
  }
  if (tid == 0) {
    int ch, it = 0;
    do {
      ch = __hip_atomic_load(iflags + CHOSEN, __ATOMIC_ACQUIRE, __HIP_MEMORY_SCOPE_AGENT);
    } while ((ch < 1 || ch > 16) && ++it < (1 << 24));
    int xcc = __builtin_amdgcn_s_getreg(XCC_GETREG) & 15;
    int role = -1;
    if (xcc == ch - 1) {
      int tk = __hip_atomic_fetch_add(iflags + TICKET, 1, __ATOMIC_RELAXED,
                                      __HIP_MEMORY_SCOPE_AGENT);
      if (tk < NROLE) role = tk;
    }
    s_i[0] = role;
  }
  __syncthreads();
  const int role = s_i[0];
  if (role < 0) return;

  // ---- init B: embt = tanh(emb_raw) ---------------------------------------
  for (int i = role * 512 + tid; i < 65536; i += NROLE * 512)
    stc(ws + OFF_EMBT + i, tanhf(emb_raw[i]));
  __syncthreads();
  if (tid == 0) post(iflags + FBAR(role), 1);
  if (tid < NROLE) wait1(iflags + FBAR(tid), 1);
  __syncthreads();

  // ---- init C: WPEt / WVP0Et tables ---------------------------------------
  for (int n = role; n < 512; n += NROLE) {
    const float* wmat = (n < 256) ? WV_present : WV_past;  // layer-0 slice
    int cls = n & 255;
    int c = tid & 255, s2 = tid >> 8;
    float acc = 0.f;
    for (int k = 128 * s2; k < 128 * s2 + 128; ++k)
      acc += wmat[c * 256 + k] * ws[OFF_EMBT + cls * 256 + k];
    s_p[s2 * 256 + c] = acc;
    __syncthreads();
    if (tid < 256)
      stc(ws + ((n < 256) ? OFF_WPET : OFF_WVPET) + cls * 256 + tid, s_p[tid] + s_p[256 + tid]);
    __syncthreads();
  }
  __syncthreads();
  if (tid == 0) post(iflags + FBAR(role), 2);
  if (tid < NROLE) wait1(iflags + FBAR(tid), 2);
  __syncthreads();
  __builtin_amdgcn_fence(__ATOMIC_ACQUIRE, "agent");   // invalidate stale L1
  __syncthreads();

  int budget = 1 << 22;

  // =========================================================================
  if (role == 0) {
    // ------------------------- sampler -------------------------------------
    const int c = tid & 255, s2 = tid >> 8;
    float we[128];
#pragma unroll
    for (int i = 0; i < 128; ++i) we[i] = end_w[c * 256 + 128 * s2 + i];
    const float eb = end_b[c];
    const float b10 = W_o_b[10 * 256 + c];
    float* zA = ws + OFF_Z + (10 * 2 + 0) * 256;
    float* zB = ws + OFF_Z + (10 * 2 + 1) * 256;
    float* ring10 = ws + OFF_RINGS + 512 * 1023;
    const int lane = tid & 63, w = tid >> 6;
    if (tid == 0) iflags[FIDX] = (1 << 8) | 127;

    for (int t = 0; t < T_STEPS; ++t) {
      float u = samples[t];
      if (tid < 2) wait_l2(iflags + FZ(10, 0) + tid * 32, t + 1, budget);
      __syncthreads();
      if (tid < 256) {
        float a = ld_f32_l2(zA + tid);
        float b = ld_f32_l2(zB + tid);
        float r3 = ld_f32_l2(ring10 + (t & 2047) * 256 + tid);
        s_x[tid] = fmaxf(a + b + b10 + r3, 0.f);
      }
      __syncthreads();
      float acc = 0.f;
#pragma unroll
      for (int i = 0; i < 128; ++i) acc += we[i] * s_x[128 * s2 + i];
      s_p[s2 * 256 + c] = acc;
      __syncthreads();
      float logit = 0.f;
      if (tid < 256) logit = s_p[tid] + s_p[256 + tid] + eb;
      float vmax = (tid < 256) ? logit : -3.4e38f;
#pragma unroll
      for (int d = 32; d > 0; d >>= 1) vmax = fmaxf(vmax, __shfl_xor(vmax, d, 64));
      if (lane == 0) s_m[280 + w] = vmax;
      __syncthreads();
      float mx = fmaxf(fmaxf(s_m[280], s_m[281]), fmaxf(s_m[282], s_m[283]));
      float e = (tid < 256) ? expf(logit - mx) : 0.f;
      float vs = e;
#pragma unroll
      for (int d = 32; d > 0; d >>= 1) vs += __shfl_xor(vs, d, 64);
      if (lane == 0) s_m[288 + w] = vs;
      __syncthreads();
      float ssum = s_m[288] + s_m[289] + s_m[290] + s_m[291];
      float p = (tid < 256) ? (e / ssum) : 0.f;
      float v = p;
#pragma unroll
      for (int d = 1; d < 64; d <<= 1) {
        float o = __shfl_up(v, (unsigned)d, 64);
        if (lane >= d) v += o;
      }
      if (tid < 256 && lane == 63) s_m[256 + w] = v;
      __syncthreads();
      float offs = 0.f;
      if (tid < 256) for (int k = 0; k < w; ++k) offs += s_m[256 + k];
      float cum = v + offs;
      unsigned long long msk = __ballot(tid < 256 && (cum > u));
      if (lane == 0) s_mask[w] = msk;
      __syncthreads();
      if (tid == 0) {
        int idx = 0;
        for (int k = 0; k < 4; ++k) {
          unsigned long long m2 = s_mask[k];
          if (m2) { idx = k * 64 + (int)__builtin_ctzll(m2); break; }
        }
        iflags[FIDX] = ((t + 2) << 8) | idx;
        out[t] = idx;
      }
      __syncthreads();
    }

  } else if (role == 1) {
    // ------------------------- L0: idx -> x1 --------------------------------
    float wo0[128];
    { int c = tid & 255, s2 = tid >> 8;
#pragma unroll
      for (int i = 0; i < 128; ++i) wo0[i] = W_o_w[c * 256 + 128 * s2 + i]; }
    const float b0 = W_o_b[tid & 255];
    for (int e = tid; e < 4096; e += 512) {
      int f = e >> 8, r = e & 255;
      float a = 0.f;
      for (int q = 0; q < 80; ++q) a += condW[r * 80 + q] * y[q * 16 + f];
      s_cond[f * 256 + r] = a;
    }
    __syncthreads();
    float* x1 = ws + OFF_Z;                 // slot (0,0)
    int pidx = 127;

    for (int t = 0; t < T_STEPS; ++t) {
      float tapv = 0.f;
      if (tid < 256 && t > 0) tapv = ws[OFF_WVPET + pidx * 256 + tid];  // prefetch
      if (tid == 0) {
        int v = wait_l2(iflags + FIDX, (t + 1) << 8, budget);
        s_i[1] = v & 255;
      }
      __syncthreads();
      const int idx = s_i[1];
      if (tid < 256) {
        s_x[tid] = ws[OFF_EMBT + idx * 256 + tid];
        float hv = s_cond[(t >> 7) * 256 + tid] + ws[OFF_WPET + idx * 256 + tid] + tapv;
        s_h[tid] = fmaxf(hv, 0.f);
      }
      __syncthreads();
      { // two 64-chunk accumulators per half — bit-exact with round-0 stage-0
        int c = tid & 255, s2 = tid >> 8;
        float a0 = 0.f, a1 = 0.f;
#pragma unroll
        for (int i = 0; i < 64; ++i) a0 += wo0[i] * s_h[128 * s2 + i];
#pragma unroll
        for (int i = 0; i < 64; ++i) a1 += wo0[64 + i] * s_h[128 * s2 + 64 + i];
        s_p[s2 * 256 + c] = a0 + a1;
      }
      __syncthreads();
      if (tid < 256)
        x1[tid] = fmaxf(s_p[tid] + s_p[256 + tid] + b0 + s_x[tid], 0.f);
      drain();
      __syncthreads();
      if (tid == 0) iflags[FZ(0, 0)] = t + 1;
      pidx = idx;
    }

  } else if (role <= 21) {
    // ------------------------- layer stages A/B (j = 1..10) -----------------
    const int jj = (role <= 11) ? (role - 1) : (role - 11);
    const int side = (role <= 11) ? 0 : 1;
    const int base = side * 128;
    float wp[64], wo[64];
    { const float* W = WV_present + jj * 65536;
      int r = tid & 127, s = tid >> 7;
#pragma unroll
      for (int i = 0; i < 64; ++i) wp[i] = W[(base + r) * 256 + 64 * s + i]; }
    { const float* W = W_o_w + jj * 65536;
      int c = tid & 255, s2 = tid >> 8;
#pragma unroll
      for (int i = 0; i < 64; ++i) wo[i] = W[c * 256 + base + 64 * s2 + i]; }
    const float bprev = W_o_b[(jj - 1) * 256 + (tid & 255)];
    for (int e = tid; e < 2048; e += 512) {
      int f = e >> 7, rr = e & 127;
      float a = 0.f;
      for (int q = 0; q < 80; ++q) a += condW[(jj * 256 + base + rr) * 80 + q] * y[q * 16 + f];
      s_cond[f * 128 + rr] = a;
    }
    __syncthreads();
    const int dj = 1 << jj, maskj = 2 * dj - 1;
    const int dprev = 1 << (jj - 1), maskp = 2 * dprev - 1;
    float* ringp = ws + OFF_RINGS + 512 * (dprev - 1);
    float* ringj = ws + OFF_RINGS + 512 * (dj - 1);
    float* zpa = ws + OFF_Z + ((jj - 1) * 2 + 0) * 256;
    float* zpb = ws + OFF_Z + ((jj - 1) * 2 + 1) * 256;
    float* zout = ws + OFF_Z + (jj * 2 + side) * 256;
    float* tapj = ws + OFF_TAPS + (jj - 1) * 16 * 256;
    const int nz = (jj == 1) ? 1 : 2;

    for (int t = 0; t < T_STEPS; ++t) {
      if (tid < nz) wait_l2(iflags + FZ(jj - 1, 0) + tid * 32, t + 1, budget);
      if (tid == 2) wait_l2(iflags + FTAP(jj), t + 1, budget);
      __syncthreads();
      float tv = 0.f;
      if (tid < 256) {
        float xv;
        if (jj == 1) {
          xv = ld_f32_l2(zpa + tid);          // x1 arrives fully formed
        } else {
          float a = ld_f32_l2(zpa + tid);
          float b = ld_f32_l2(zpb + tid);
          float r3 = ld_f32_l2(ringp + (t & maskp) * 256 + tid);
          xv = fmaxf(a + b + bprev + r3, 0.f);
        }
        s_x[tid] = xv;
        if (side == 0) ringj[(t & maskj) * 256 + tid] = xv;   // plain write-through
      }
      if (tid < 128) tv = ld_f32_l2(tapj + (t & 15) * 256 + base + tid);
      __syncthreads();
      { int r = tid & 127, s = tid >> 7;
        float acc = 0.f;
#pragma unroll
        for (int i = 0; i < 64; ++i) acc += wp[i] * s_x[64 * s + i];
        s_p[s * 128 + r] = acc; }
      __syncthreads();
      if (tid < 128) {
        int f = t >> 7;
        float hv = s_p[tid] + s_p[128 + tid] + s_p[256 + tid] + s_p[384 + tid]
                 + s_cond[f * 128 + tid] + tv;
        s_h[tid] = fmaxf(hv, 0.f);
      }
      __syncthreads();
      { int cc = tid & 255, s2 = tid >> 8;
        float acc = 0.f;
#pragma unroll
        for (int i = 0; i < 64; ++i) acc += wo[i] * s_h[64 * s2 + i];
        s_p[s2 * 256 + cc] = acc; }
      __syncthreads();
      if (tid < 256) zout[tid] = s_p[tid] + s_p[256 + tid];
      drain();
      __syncthreads();
      if (tid == 0) iflags[FZ(jj, side)] = t + 1;
    }

  } else {
    // ------------------------- tap helpers (j = 1..10) ----------------------
    const int j = role - 21;
    const int dj = 1 << j, maskj = 2 * dj - 1;
    float wq[128];
    { const float* W = WV_past + j * 65536;
      int r = tid & 255, s2 = tid >> 8;
#pragma unroll
      for (int i = 0; i < 128; ++i) wq[i] = W[r * 256 + 128 * s2 + i]; }
    float* ringj = ws + OFF_RINGS + 512 * (dj - 1);
    float* tapj = ws + OFF_TAPS + (j - 1) * 16 * 256;
    const int lag = (dj < 16) ? dj : 16;

    for (int t = 0; t < T_STEPS; ++t) {
      int want = t - lag + 1;
      if (tid == 0 && want >= 1) wait_l2(iflags + FZ(j, 0), want, budget);
      __syncthreads();
      if (t >= dj) {
        if (tid < 256) s_x[tid] = ld_f32_l2(ringj + ((t - dj) & maskj) * 256 + tid);
        __syncthreads();
        int r = tid & 255, s2 = tid >> 8;
        float acc = 0.f;
#pragma unroll
        for (int i = 0; i < 128; ++i) acc += wq[i] * s_x[128 * s2 + i];
        s_p[s2 * 256 + r] = acc;
        __syncthreads();
        if (tid < 256) tapj[(t & 15) * 256 + tid] = s_p[tid] + s_p[256 + tid];
      } else {
        if (tid < 256) tapj[(t & 15) * 256 + tid] = 0.f;
      }
      drain();
      __syncthreads();
      if (tid == 0) iflags[FTAP(j)] = t + 1;
    }
  }
}

extern "C" void kernel_launch(void* const* d_in, const int* in_sizes, int n_in,
                              void* d_out, int out_size, void* d_ws, size_t ws_size,
                              hipStream_t stream) {
  const float* y       = (const float*)d_in[0];
  const float* samples = (const float*)d_in[1];
  const float* emb_raw = (const float*)d_in[2];
  const float* condW   = (const float*)d_in[3];
  const float* WV_past = (const float*)d_in[4];
  const float* WV_pres = (const float*)d_in[5];
  const float* W_o_w   = (const float*)d_in[6];
  const float* W_o_b   = (const float*)d_in[7];
  const float* end_w   = (const float*)d_in[8];
  const float* end_b   = (const float*)d_in[9];
  (void)in_sizes; (void)n_in; (void)out_size; (void)ws_size;
  hipLaunchKernelGGL(fftnet_kernel, dim3(NBLK), dim3(512), 0, stream,
                     y, samples, emb_raw, condW, WV_past, WV_pres,
                     W_o_w, W_o_b, end_w, end_b, (int*)d_out, (float*)d_ws);
}

// Round 5
// 56099.969 us; speedup vs baseline: 1.1461x; 1.1461x over previous
//
#include <hip/hip_runtime.h>
#include <math.h>

// ---------------------------------------------------------------------------
// FastFFTNet autoregressive sampler on MI355X — round 5: tagged-payload
// pipeline. All cross-block handoffs are 8-byte {value, step-tag} pairs via
// relaxed AGENT-scope atomics (R0-proven coherence class). No flags, no
// producer drains on the critical path: consumers spin directly on tags.
//
// Roles (32 blocks x 512 thr): 0 sampler | 1 L0 | 2..11 A_j (j=role-1)
//   12..21 B_j (j=role-11) | 22..31 helper_j (j=role-21, past taps)
// Chain/step: FIDX -> L0 -> xq_1 -> [A1B1] -> z1,xq.. -> ... -> z10,xq10 -> sampler
// ---------------------------------------------------------------------------

#define T_STEPS 2048
#define NROLE   32

typedef unsigned long long u64;

// ws float offsets
#define OFF_EMBT   0           // tanh(emb_raw)           [256][256]
#define OFF_WPET   65536       // WV_present[0] @ emb^T   [class][256]
#define OFF_WVPET  131072      // WV_past[0]    @ emb^T   [class][256]
#define OFF_RINGS  196608      // ring_j (plain f32) at +512*((1<<j)-1), 512<<j floats
#define OFF_TAPQ   1244672     // pairs [10][32][256]
#define OFF_ZQ     1408512     // pairs [11][2][256] (j=1..10 used)
#define OFF_XQ     1419776     // pairs [11][256]    (x_j; j=1 from L0, j>=2 from A_j)
#define WS_FLOATS  1425408

#define FIDX     0             // int index into iflags
#define FBAR(r)  (32 + 32*(r)) // init barriers; poison-safe monotone

// ---- agent-scope primitives (R0-proven coherence class) -------------------
__device__ __forceinline__ float ldc(const float* p) {
  int v = __hip_atomic_load((const int*)p, __ATOMIC_RELAXED, __HIP_MEMORY_SCOPE_AGENT);
  return __int_as_float(v);
}
__device__ __forceinline__ void stc(float* p, float x) {
  __hip_atomic_store((int*)p, __float_as_int(x), __ATOMIC_RELAXED, __HIP_MEMORY_SCOPE_AGENT);
}
__device__ __forceinline__ u64 ldq(const u64* p) {
  return __hip_atomic_load(p, __ATOMIC_RELAXED, __HIP_MEMORY_SCOPE_AGENT);
}
__device__ __forceinline__ void stq(u64* p, float v, int tag) {
  u64 x = (u64)(unsigned)__float_as_int(v) | ((u64)(unsigned)tag << 32);
  __hip_atomic_store(p, x, __ATOMIC_RELAXED, __HIP_MEMORY_SCOPE_AGENT);
}
__device__ __forceinline__ int ptag(u64 q) { return (int)(q >> 32); }
__device__ __forceinline__ float pval(u64 q) { return __int_as_float((int)(unsigned)q); }

__device__ __forceinline__ float spin_pair(const u64* p, int want) {
  int bud = 1 << 20; u64 q;
  do { q = ldq(p); } while (ptag(q) < want && --bud > 0);
  return pval(q);
}
// batched 3-pair poll: values stable once tagged (chain backpressure)
__device__ __forceinline__ void spin3(const u64* p1, const u64* p2, const u64* p3,
                                      int want, float& v1, float& v2, float& v3) {
  int bud = 1 << 20; u64 q1, q2, q3; bool ok;
  do {
    q1 = ldq(p1); q2 = ldq(p2); q3 = ldq(p3);
    ok = (ptag(q1) >= want) & (ptag(q2) >= want) & (ptag(q3) >= want);
  } while (!ok && --bud > 0);
  v1 = pval(q1); v2 = pval(q2); v3 = pval(q3);
}
__device__ __forceinline__ void spin_tag2(const u64* p1, const u64* p2, int w1, int w2) {
  int bud = 1 << 20; u64 q1, q2; bool ok;
  do {
    q1 = ldq(p1); q2 = ldq(p2);
    ok = (ptag(q1) >= w1) & (ptag(q2) >= w2);
  } while (!ok && --bud > 0);
}
// init-phase flag prims (R0-proven)
__device__ __forceinline__ void wait1(int* f, int want) {
  int it = 0;
  while (__hip_atomic_load(f, __ATOMIC_RELAXED, __HIP_MEMORY_SCOPE_AGENT) < want) {
    if (++it > (1 << 22)) break;
  }
  (void)__hip_atomic_load(f, __ATOMIC_ACQUIRE, __HIP_MEMORY_SCOPE_AGENT);
}
__device__ __forceinline__ void post(int* f, int v) {
  __hip_atomic_store(f, v, __ATOMIC_RELEASE, __HIP_MEMORY_SCOPE_AGENT);
}

__global__ __launch_bounds__(512, 2)
void fftnet_kernel(const float* __restrict__ y, const float* __restrict__ samples,
                   const float* __restrict__ emb_raw, const float* __restrict__ condW,
                   const float* __restrict__ WV_past, const float* __restrict__ WV_present,
                   const float* __restrict__ W_o_w, const float* __restrict__ W_o_b,
                   const float* __restrict__ end_w, const float* __restrict__ end_b,
                   int* __restrict__ out, float* __restrict__ ws)
{
  const int tid = threadIdx.x;
  const int role = blockIdx.x;
  int* iflags = (int*)(ws + WS_FLOATS);
  u64* zq  = (u64*)(ws + OFF_ZQ);
  u64* xq  = (u64*)(ws + OFF_XQ);
  u64* tq  = (u64*)(ws + OFF_TAPQ);

  __shared__ float s_x[256];
  __shared__ float s_h[256];
  __shared__ float s_p[1024];
  __shared__ float s_cond[16 * 256];
  __shared__ float s_tap[128];
  __shared__ float s_m[320];
  __shared__ unsigned long long s_mask[8];

  // ---- init B: embt = tanh(emb_raw) ---------------------------------------
  for (int i = role * 512 + tid; i < 65536; i += NROLE * 512)
    stc(ws + OFF_EMBT + i, tanhf(emb_raw[i]));
  __syncthreads();
  if (tid == 0) post(iflags + FBAR(role), 1);
  if (tid < NROLE) wait1(iflags + FBAR(tid), 1);
  __syncthreads();

  // ---- init C: WPEt / WVP0Et tables ---------------------------------------
  for (int n = role; n < 512; n += NROLE) {
    const float* wmat = (n < 256) ? WV_present : WV_past;  // layer-0 slice
    int cls = n & 255;
    int c = tid & 255, s2 = tid >> 8;
    float acc = 0.f;
    for (int k = 128 * s2; k < 128 * s2 + 128; ++k)
      acc += wmat[c * 256 + k] * ws[OFF_EMBT + cls * 256 + k];
    s_p[s2 * 256 + c] = acc;
    __syncthreads();
    if (tid < 256)
      stc(ws + ((n < 256) ? OFF_WPET : OFF_WVPET) + cls * 256 + tid, s_p[tid] + s_p[256 + tid]);
    __syncthreads();
  }
  __syncthreads();
  if (tid == 0) post(iflags + FBAR(role), 2);
  if (tid < NROLE) wait1(iflags + FBAR(tid), 2);
  __syncthreads();
  __builtin_amdgcn_fence(__ATOMIC_ACQUIRE, "agent");   // invalidate stale L1
  __syncthreads();

  // =========================================================================
  if (role == 0) {
    // ------------------------- sampler -------------------------------------
    const int c = tid & 255, s2 = tid >> 8;
    float we[128];
#pragma unroll
    for (int i = 0; i < 128; ++i) we[i] = end_w[c * 256 + 128 * s2 + i];
#pragma unroll
    for (int i = 0; i < 128; ++i) asm volatile("" : "+v"(we[i]));
    const float eb = end_b[c];
    const float b10 = W_o_b[10 * 256 + c];
    const u64* pza = zq + (10 * 2 + 0) * 256;
    const u64* pzb = zq + (10 * 2 + 1) * 256;
    const u64* pxq = xq + 10 * 256;
    const int lane = tid & 63, w = tid >> 6;
    if (tid == 0)
      __hip_atomic_store(iflags + FIDX, (1 << 8) | 127, __ATOMIC_RELAXED,
                         __HIP_MEMORY_SCOPE_AGENT);

    for (int t = 0; t < T_STEPS; ++t) {
      float u = samples[t];
      if (tid < 256) {
        float a, b, r3;
        spin3(pza + tid, pzb + tid, pxq + tid, t + 1, a, b, r3);
        s_x[tid] = fmaxf(a + b + b10 + r3, 0.f);
      }
      __syncthreads();
      float acc = 0.f;
#pragma unroll
      for (int i = 0; i < 128; ++i) acc += we[i] * s_x[128 * s2 + i];
      s_p[s2 * 256 + c] = acc;
      __syncthreads();
      float logit = 0.f;
      if (tid < 256) logit = s_p[tid] + s_p[256 + tid] + eb;
      float vmax = (tid < 256) ? logit : -3.4e38f;
#pragma unroll
      for (int d = 32; d > 0; d >>= 1) vmax = fmaxf(vmax, __shfl_xor(vmax, d, 64));
      if (lane == 0) s_m[280 + w] = vmax;
      __syncthreads();
      float mx = fmaxf(fmaxf(s_m[280], s_m[281]), fmaxf(s_m[282], s_m[283]));
      float e = (tid < 256) ? expf(logit - mx) : 0.f;
      float vs = e;
#pragma unroll
      for (int d = 32; d > 0; d >>= 1) vs += __shfl_xor(vs, d, 64);
      if (lane == 0) s_m[288 + w] = vs;
      __syncthreads();
      float ssum = s_m[288] + s_m[289] + s_m[290] + s_m[291];
      float p = (tid < 256) ? (e / ssum) : 0.f;
      float v = p;
#pragma unroll
      for (int d = 1; d < 64; d <<= 1) {
        float o = __shfl_up(v, (unsigned)d, 64);
        if (lane >= d) v += o;
      }
      if (tid < 256 && lane == 63) s_m[256 + w] = v;
      __syncthreads();
      float offs = 0.f;
      if (tid < 256) for (int k = 0; k < w; ++k) offs += s_m[256 + k];
      float cum = v + offs;
      unsigned long long msk = __ballot(tid < 256 && (cum > u));
      if (lane == 0) s_mask[w] = msk;
      __syncthreads();
      if (tid == 0) {
        int idx = 0;
        for (int k = 0; k < 4; ++k) {
          unsigned long long m2 = s_mask[k];
          if (m2) { idx = k * 64 + (int)__builtin_ctzll(m2); break; }
        }
        __hip_atomic_store(iflags + FIDX, ((t + 2) << 8) | idx, __ATOMIC_RELAXED,
                           __HIP_MEMORY_SCOPE_AGENT);
        out[t] = idx;
      }
      __syncthreads();
    }

  } else if (role == 1) {
    // ------------------------- L0: idx -> x1 (tagged) -----------------------
    float wo0[128];
    { int c = tid & 255, s2 = tid >> 8;
#pragma unroll
      for (int i = 0; i < 128; ++i) wo0[i] = W_o_w[c * 256 + 128 * s2 + i]; }
#pragma unroll
    for (int i = 0; i < 128; ++i) asm volatile("" : "+v"(wo0[i]));
    const float b0 = W_o_b[tid & 255];
    for (int e = tid; e < 4096; e += 512) {
      int f = e >> 8, r = e & 255;
      float a = 0.f;
      for (int q = 0; q < 80; ++q) a += condW[r * 80 + q] * y[q * 16 + f];
      s_cond[f * 256 + r] = a;
    }
    __syncthreads();
    u64* px1 = xq + 1 * 256;
    int pidx = 127;

    for (int t = 0; t < T_STEPS; ++t) {
      float tapv = 0.f;
      if (tid < 256 && t > 0) tapv = ws[OFF_WVPET + pidx * 256 + tid];  // prefetch
      int v, bud = 1 << 20;
      do {
        v = __hip_atomic_load(iflags + FIDX, __ATOMIC_RELAXED, __HIP_MEMORY_SCOPE_AGENT);
      } while (v < ((t + 1) << 8) && --bud > 0);
      const int idx = v & 255;
      if (tid < 256) {
        s_x[tid] = ws[OFF_EMBT + idx * 256 + tid];
        float hv = s_cond[(t >> 7) * 256 + tid] + ws[OFF_WPET + idx * 256 + tid] + tapv;
        s_h[tid] = fmaxf(hv, 0.f);
      }
      __syncthreads();
      { // two 64-chunk accumulators per half — bit-exact (R3-proven)
        int c = tid & 255, s2 = tid >> 8;
        float a0 = 0.f, a1 = 0.f;
#pragma unroll
        for (int i = 0; i < 64; ++i) a0 += wo0[i] * s_h[128 * s2 + i];
#pragma unroll
        for (int i = 0; i < 64; ++i) a1 += wo0[64 + i] * s_h[128 * s2 + 64 + i];
        s_p[s2 * 256 + c] = a0 + a1;
      }
      __syncthreads();
      if (tid < 256)
        stq(px1 + tid, fmaxf(s_p[tid] + s_p[256 + tid] + b0 + s_x[tid], 0.f), t + 1);
      pidx = idx;
    }

  } else if (role <= 21) {
    // ------------------------- layer stages A/B (j = 1..10) -----------------
    const int jj = (role <= 11) ? (role - 1) : (role - 11);
    const int side = (role <= 11) ? 0 : 1;
    const int base = side * 128;
    float wp[64], wo[64];
    { const float* W = WV_present + jj * 65536;
      int r = tid & 127, s = tid >> 7;
#pragma unroll
      for (int i = 0; i < 64; ++i) wp[i] = W[(base + r) * 256 + 64 * s + i]; }
    { const float* W = W_o_w + jj * 65536;
      int c = tid & 255, s2 = tid >> 8;
#pragma unroll
      for (int i = 0; i < 64; ++i) wo[i] = W[c * 256 + base + 64 * s2 + i]; }
#pragma unroll
    for (int i = 0; i < 64; ++i) asm volatile("" : "+v"(wp[i]), "+v"(wo[i]));
    const float bprev = W_o_b[(jj - 1) * 256 + (tid & 255)];
    for (int e = tid; e < 2048; e += 512) {
      int f = e >> 7, rr = e & 127;
      float a = 0.f;
      for (int q = 0; q < 80; ++q) a += condW[(jj * 256 + base + rr) * 80 + q] * y[q * 16 + f];
      s_cond[f * 128 + rr] = a;
    }
    __syncthreads();
    const int dj = 1 << jj, maskj = 2 * dj - 1;
    float* ringj = ws + OFF_RINGS + 512 * (dj - 1);
    const u64* pza = zq + ((jj - 1) * 2 + 0) * 256;
    const u64* pzb = zq + ((jj - 1) * 2 + 1) * 256;
    const u64* pxp = xq + (jj - 1) * 256;    // x_{j-1}; jj==1 -> xq_1 from L0
    u64* zout = zq + (jj * 2 + side) * 256;
    u64* xout = xq + jj * 256;               // published by side 0, jj>=2
    const u64* ptap = tq + (jj - 1) * 32 * 256;

    for (int t = 0; t < T_STEPS; ++t) {
      const int want = t + 1;
      if (tid < 256) {
        float xv;
        if (jj == 1) {
          xv = spin_pair(xq + 1 * 256 + tid, want);       // x1 fully formed
        } else {
          float a, b, r3;
          spin3(pza + tid, pzb + tid, pxp + tid, want, a, b, r3);
          xv = fmaxf(a + b + bprev + r3, 0.f);
        }
        s_x[tid] = xv;
        if (side == 0) {
          stc(ringj + (t & maskj) * 256 + tid, xv);       // for tap helper
          if (jj >= 2) stq(xout + tid, xv, want);         // early x publish
        }
      } else if (tid < 384) {
        int l = tid - 256;
        s_tap[l] = spin_pair(ptap + (t & 31) * 256 + base + l, want);
      }
      __syncthreads();
      { int r = tid & 127, s = tid >> 7;
        float acc = 0.f;
#pragma unroll
        for (int i = 0; i < 64; ++i) acc += wp[i] * s_x[64 * s + i];
        s_p[s * 128 + r] = acc; }
      __syncthreads();
      if (tid < 128) {
        int f = t >> 7;
        float hv = s_p[tid] + s_p[128 + tid] + s_p[256 + tid] + s_p[384 + tid]
                 + s_cond[f * 128 + tid] + s_tap[tid];
        s_h[tid] = fmaxf(hv, 0.f);
      }
      __syncthreads();
      { int cc = tid & 255, s2 = tid >> 8;
        float acc = 0.f;
#pragma unroll
        for (int i = 0; i < 64; ++i) acc += wo[i] * s_h[64 * s2 + i];
        s_p[s2 * 256 + cc] = acc; }
      __syncthreads();
      if (side == 0)
        __builtin_amdgcn_fence(__ATOMIC_RELEASE, "agent");  // ring visible before z tag
      if (tid < 256) stq(zout + tid, s_p[tid] + s_p[256 + tid], want);
    }

  } else {
    // ------------------------- tap helpers (j = 1..10) ----------------------
    const int j = role - 21;
    const int dj = 1 << j, maskj = 2 * dj - 1;
    float wq[128];
    { const float* W = WV_past + j * 65536;
      int r = tid & 255, s2 = tid >> 8;
#pragma unroll
      for (int i = 0; i < 128; ++i) wq[i] = W[r * 256 + 128 * s2 + i]; }
#pragma unroll
    for (int i = 0; i < 128; ++i) asm volatile("" : "+v"(wq[i]));
    float* ringj = ws + OFF_RINGS + 512 * (dj - 1);
    u64* tapj = tq + (j - 1) * 32 * 256;
    const u64* pza = zq + (j * 2 + 0) * 256;
    const u64* pzb = zq + (j * 2 + 1) * 256;

    for (int t = 0; t < T_STEPS; ++t) {
      // gates: ring(t-dj) visible via z_jA tag (fence-ordered);
      // tap-slot clobber safety: both halves past step t-32.
      int wgA = (t >= dj) ? (t - dj + 1) : (t - 31);
      if (wgA < t - 31) wgA = t - 31;
      int wgB = t - 31;
      if (tid < 256 && (wgA >= 1 || wgB >= 1))
        spin_tag2(pza + tid, pzb + tid, wgA, wgB);
      float tapv = 0.f;
      if (t >= dj) {
        if (tid < 256) s_x[tid] = ldc(ringj + ((t - dj) & maskj) * 256 + tid);
        __syncthreads();
        int r = tid & 255, s2 = tid >> 8;
        float acc = 0.f;
#pragma unroll
        for (int i = 0; i < 128; ++i) acc += wq[i] * s_x[128 * s2 + i];
        s_p[s2 * 256 + r] = acc;
        __syncthreads();
        if (tid < 256) tapv = s_p[tid] + s_p[256 + tid];
      }
      if (tid < 256) stq(tapj + (t & 31) * 256 + tid, tapv, t + 1);
      __syncthreads();
    }
  }
}

extern "C" void kernel_launch(void* const* d_in, const int* in_sizes, int n_in,
                              void* d_out, int out_size, void* d_ws, size_t ws_size,
                              hipStream_t stream) {
  const float* y       = (const float*)d_in[0];
  const float* samples = (const float*)d_in[1];
  const float* emb_raw = (const float*)d_in[2];
  const float* condW   = (const float*)d_in[3];
  const float* WV_past = (const float*)d_in[4];
  const float* WV_pres = (const float*)d_in[5];
  const float* W_o_w   = (const float*)d_in[6];
  const float* W_o_b   = (const float*)d_in[7];
  const float* end_w   = (const float*)d_in[8];
  const float* end_b   = (const float*)d_in[9];
  (void)in_sizes; (void)n_in; (void)out_size; (void)ws_size;
  hipLaunchKernelGGL(fftnet_kernel, dim3(NROLE), dim3(512), 0, stream,
                     y, samples, emb_raw, condW, WV_past, WV_pres,
                     W_o_w, W_o_b, end_w, end_b, (int*)d_out, (float*)d_ws);
}

// Round 6
// 56030.469 us; speedup vs baseline: 1.1475x; 1.0012x over previous
//
#include <hip/hip_runtime.h>
#include <math.h>

// ---------------------------------------------------------------------------
// FastFFTNet autoregressive sampler on MI355X — round 6: R5 tagged-payload
// pipeline with the register spill fixed. Single change vs R5 (passed,
// absmax 0): __launch_bounds__(512, 1) so per-thread weight arrays
// (wp/wo/we/wq/wo0) are truly VGPR-resident (R5 showed VGPR_Count=100 ->
// ~60 spilled floats/thread reloaded from scratch every step on every
// critical-path stage). No arithmetic, protocol, or comm changes.
//
// Roles (32 blocks x 512 thr): 0 sampler | 1 L0 | 2..11 A_j (j=role-1)
//   12..21 B_j (j=role-11) | 22..31 helper_j (j=role-21, past taps)
// Chain/step: FIDX -> L0 -> xq_1 -> [A1B1] -> z1,xq.. -> ... -> z10,xq10 -> sampler
// ---------------------------------------------------------------------------

#define T_STEPS 2048
#define NROLE   32

typedef unsigned long long u64;

// ws float offsets
#define OFF_EMBT   0           // tanh(emb_raw)           [256][256]
#define OFF_WPET   65536       // WV_present[0] @ emb^T   [class][256]
#define OFF_WVPET  131072      // WV_past[0]    @ emb^T   [class][256]
#define OFF_RINGS  196608      // ring_j (plain f32) at +512*((1<<j)-1), 512<<j floats
#define OFF_TAPQ   1244672     // pairs [10][32][256]
#define OFF_ZQ     1408512     // pairs [11][2][256] (j=1..10 used)
#define OFF_XQ     1419776     // pairs [11][256]    (x_j; j=1 from L0, j>=2 from A_j)
#define WS_FLOATS  1425408

#define FIDX     0             // int index into iflags
#define FBAR(r)  (32 + 32*(r)) // init barriers; poison-safe monotone

// ---- agent-scope primitives (proven coherence class) ----------------------
__device__ __forceinline__ float ldc(const float* p) {
  int v = __hip_atomic_load((const int*)p, __ATOMIC_RELAXED, __HIP_MEMORY_SCOPE_AGENT);
  return __int_as_float(v);
}
__device__ __forceinline__ void stc(float* p, float x) {
  __hip_atomic_store((int*)p, __float_as_int(x), __ATOMIC_RELAXED, __HIP_MEMORY_SCOPE_AGENT);
}
__device__ __forceinline__ u64 ldq(const u64* p) {
  return __hip_atomic_load(p, __ATOMIC_RELAXED, __HIP_MEMORY_SCOPE_AGENT);
}
__device__ __forceinline__ void stq(u64* p, float v, int tag) {
  u64 x = (u64)(unsigned)__float_as_int(v) | ((u64)(unsigned)tag << 32);
  __hip_atomic_store(p, x, __ATOMIC_RELAXED, __HIP_MEMORY_SCOPE_AGENT);
}
__device__ __forceinline__ int ptag(u64 q) { return (int)(q >> 32); }
__device__ __forceinline__ float pval(u64 q) { return __int_as_float((int)(unsigned)q); }

__device__ __forceinline__ float spin_pair(const u64* p, int want) {
  int bud = 1 << 20; u64 q;
  do { q = ldq(p); } while (ptag(q) < want && --bud > 0);
  return pval(q);
}
// batched 3-pair poll: values stable once tagged (chain backpressure)
__device__ __forceinline__ void spin3(const u64* p1, const u64* p2, const u64* p3,
                                      int want, float& v1, float& v2, float& v3) {
  int bud = 1 << 20; u64 q1, q2, q3; bool ok;
  do {
    q1 = ldq(p1); q2 = ldq(p2); q3 = ldq(p3);
    ok = (ptag(q1) >= want) & (ptag(q2) >= want) & (ptag(q3) >= want);
  } while (!ok && --bud > 0);
  v1 = pval(q1); v2 = pval(q2); v3 = pval(q3);
}
__device__ __forceinline__ void spin_tag2(const u64* p1, const u64* p2, int w1, int w2) {
  int bud = 1 << 20; u64 q1, q2; bool ok;
  do {
    q1 = ldq(p1); q2 = ldq(p2);
    ok = (ptag(q1) >= w1) & (ptag(q2) >= w2);
  } while (!ok && --bud > 0);
}
// init-phase flag prims (R0-proven)
__device__ __forceinline__ void wait1(int* f, int want) {
  int it = 0;
  while (__hip_atomic_load(f, __ATOMIC_RELAXED, __HIP_MEMORY_SCOPE_AGENT) < want) {
    if (++it > (1 << 22)) break;
  }
  (void)__hip_atomic_load(f, __ATOMIC_ACQUIRE, __HIP_MEMORY_SCOPE_AGENT);
}
__device__ __forceinline__ void post(int* f, int v) {
  __hip_atomic_store(f, v, __ATOMIC_RELEASE, __HIP_MEMORY_SCOPE_AGENT);
}

__global__ __launch_bounds__(512, 1)
void fftnet_kernel(const float* __restrict__ y, const float* __restrict__ samples,
                   const float* __restrict__ emb_raw, const float* __restrict__ condW,
                   const float* __restrict__ WV_past, const float* __restrict__ WV_present,
                   const float* __restrict__ W_o_w, const float* __restrict__ W_o_b,
                   const float* __restrict__ end_w, const float* __restrict__ end_b,
                   int* __restrict__ out, float* __restrict__ ws)
{
  const int tid = threadIdx.x;
  const int role = blockIdx.x;
  int* iflags = (int*)(ws + WS_FLOATS);
  u64* zq  = (u64*)(ws + OFF_ZQ);
  u64* xq  = (u64*)(ws + OFF_XQ);
  u64* tq  = (u64*)(ws + OFF_TAPQ);

  __shared__ float s_x[256];
  __shared__ float s_h[256];
  __shared__ float s_p[1024];
  __shared__ float s_cond[16 * 256];
  __shared__ float s_tap[128];
  __shared__ float s_m[320];
  __shared__ unsigned long long s_mask[8];

  // ---- init B: embt = tanh(emb_raw) ---------------------------------------
  for (int i = role * 512 + tid; i < 65536; i += NROLE * 512)
    stc(ws + OFF_EMBT + i, tanhf(emb_raw[i]));
  __syncthreads();
  if (tid == 0) post(iflags + FBAR(role), 1);
  if (tid < NROLE) wait1(iflags + FBAR(tid), 1);
  __syncthreads();

  // ---- init C: WPEt / WVP0Et tables ---------------------------------------
  for (int n = role; n < 512; n += NROLE) {
    const float* wmat = (n < 256) ? WV_present : WV_past;  // layer-0 slice
    int cls = n & 255;
    int c = tid & 255, s2 = tid >> 8;
    float acc = 0.f;
    for (int k = 128 * s2; k < 128 * s2 + 128; ++k)
      acc += wmat[c * 256 + k] * ws[OFF_EMBT + cls * 256 + k];
    s_p[s2 * 256 + c] = acc;
    __syncthreads();
    if (tid < 256)
      stc(ws + ((n < 256) ? OFF_WPET : OFF_WVPET) + cls * 256 + tid, s_p[tid] + s_p[256 + tid]);
    __syncthreads();
  }
  __syncthreads();
  if (tid == 0) post(iflags + FBAR(role), 2);
  if (tid < NROLE) wait1(iflags + FBAR(tid), 2);
  __syncthreads();
  __builtin_amdgcn_fence(__ATOMIC_ACQUIRE, "agent");   // invalidate stale L1
  __syncthreads();

  // =========================================================================
  if (role == 0) {
    // ------------------------- sampler -------------------------------------
    const int c = tid & 255, s2 = tid >> 8;
    float we[128];
#pragma unroll
    for (int i = 0; i < 128; ++i) we[i] = end_w[c * 256 + 128 * s2 + i];
    const float eb = end_b[c];
    const float b10 = W_o_b[10 * 256 + c];
    const u64* pza = zq + (10 * 2 + 0) * 256;
    const u64* pzb = zq + (10 * 2 + 1) * 256;
    const u64* pxq = xq + 10 * 256;
    const int lane = tid & 63, w = tid >> 6;
    if (tid == 0)
      __hip_atomic_store(iflags + FIDX, (1 << 8) | 127, __ATOMIC_RELAXED,
                         __HIP_MEMORY_SCOPE_AGENT);

    for (int t = 0; t < T_STEPS; ++t) {
      float u = samples[t];
      if (tid < 256) {
        float a, b, r3;
        spin3(pza + tid, pzb + tid, pxq + tid, t + 1, a, b, r3);
        s_x[tid] = fmaxf(a + b + b10 + r3, 0.f);
      }
      __syncthreads();
      float acc = 0.f;
#pragma unroll
      for (int i = 0; i < 128; ++i) acc += we[i] * s_x[128 * s2 + i];
      s_p[s2 * 256 + c] = acc;
      __syncthreads();
      float logit = 0.f;
      if (tid < 256) logit = s_p[tid] + s_p[256 + tid] + eb;
      float vmax = (tid < 256) ? logit : -3.4e38f;
#pragma unroll
      for (int d = 32; d > 0; d >>= 1) vmax = fmaxf(vmax, __shfl_xor(vmax, d, 64));
      if (lane == 0) s_m[280 + w] = vmax;
      __syncthreads();
      float mx = fmaxf(fmaxf(s_m[280], s_m[281]), fmaxf(s_m[282], s_m[283]));
      float e = (tid < 256) ? expf(logit - mx) : 0.f;
      float vs = e;
#pragma unroll
      for (int d = 32; d > 0; d >>= 1) vs += __shfl_xor(vs, d, 64);
      if (lane == 0) s_m[288 + w] = vs;
      __syncthreads();
      float ssum = s_m[288] + s_m[289] + s_m[290] + s_m[291];
      float p = (tid < 256) ? (e / ssum) : 0.f;
      float v = p;
#pragma unroll
      for (int d = 1; d < 64; d <<= 1) {
        float o = __shfl_up(v, (unsigned)d, 64);
        if (lane >= d) v += o;
      }
      if (tid < 256 && lane == 63) s_m[256 + w] = v;
      __syncthreads();
      float offs = 0.f;
      if (tid < 256) for (int k = 0; k < w; ++k) offs += s_m[256 + k];
      float cum = v + offs;
      unsigned long long msk = __ballot(tid < 256 && (cum > u));
      if (lane == 0) s_mask[w] = msk;
      __syncthreads();
      if (tid == 0) {
        int idx = 0;
        for (int k = 0; k < 4; ++k) {
          unsigned long long m2 = s_mask[k];
          if (m2) { idx = k * 64 + (int)__builtin_ctzll(m2); break; }
        }
        __hip_atomic_store(iflags + FIDX, ((t + 2) << 8) | idx, __ATOMIC_RELAXED,
                           __HIP_MEMORY_SCOPE_AGENT);
        out[t] = idx;
      }
      __syncthreads();
    }

  } else if (role == 1) {
    // ------------------------- L0: idx -> x1 (tagged) -----------------------
    float wo0[128];
    { int c = tid & 255, s2 = tid >> 8;
#pragma unroll
      for (int i = 0; i < 128; ++i) wo0[i] = W_o_w[c * 256 + 128 * s2 + i]; }
    const float b0 = W_o_b[tid & 255];
    for (int e = tid; e < 4096; e += 512) {
      int f = e >> 8, r = e & 255;
      float a = 0.f;
      for (int q = 0; q < 80; ++q) a += condW[r * 80 + q] * y[q * 16 + f];
      s_cond[f * 256 + r] = a;
    }
    __syncthreads();
    u64* px1 = xq + 1 * 256;
    int pidx = 127;

    for (int t = 0; t < T_STEPS; ++t) {
      float tapv = 0.f;
      if (tid < 256 && t > 0) tapv = ws[OFF_WVPET + pidx * 256 + tid];  // prefetch
      int v, bud = 1 << 20;
      do {
        v = __hip_atomic_load(iflags + FIDX, __ATOMIC_RELAXED, __HIP_MEMORY_SCOPE_AGENT);
      } while (v < ((t + 1) << 8) && --bud > 0);
      const int idx = v & 255;
      if (tid < 256) {
        s_x[tid] = ws[OFF_EMBT + idx * 256 + tid];
        float hv = s_cond[(t >> 7) * 256 + tid] + ws[OFF_WPET + idx * 256 + tid] + tapv;
        s_h[tid] = fmaxf(hv, 0.f);
      }
      __syncthreads();
      { // two 64-chunk accumulators per half — bit-exact (R3/R5-proven)
        int c = tid & 255, s2 = tid >> 8;
        float a0 = 0.f, a1 = 0.f;
#pragma unroll
        for (int i = 0; i < 64; ++i) a0 += wo0[i] * s_h[128 * s2 + i];
#pragma unroll
        for (int i = 0; i < 64; ++i) a1 += wo0[64 + i] * s_h[128 * s2 + 64 + i];
        s_p[s2 * 256 + c] = a0 + a1;
      }
      __syncthreads();
      if (tid < 256)
        stq(px1 + tid, fmaxf(s_p[tid] + s_p[256 + tid] + b0 + s_x[tid], 0.f), t + 1);
      pidx = idx;
    }

  } else if (role <= 21) {
    // ------------------------- layer stages A/B (j = 1..10) -----------------
    const int jj = (role <= 11) ? (role - 1) : (role - 11);
    const int side = (role <= 11) ? 0 : 1;
    const int base = side * 128;
    float wp[64], wo[64];
    { const float* W = WV_present + jj * 65536;
      int r = tid & 127, s = tid >> 7;
#pragma unroll
      for (int i = 0; i < 64; ++i) wp[i] = W[(base + r) * 256 + 64 * s + i]; }
    { const float* W = W_o_w + jj * 65536;
      int c = tid & 255, s2 = tid >> 8;
#pragma unroll
      for (int i = 0; i < 64; ++i) wo[i] = W[c * 256 + base + 64 * s2 + i]; }
    const float bprev = W_o_b[(jj - 1) * 256 + (tid & 255)];
    for (int e = tid; e < 2048; e += 512) {
      int f = e >> 7, rr = e & 127;
      float a = 0.f;
      for (int q = 0; q < 80; ++q) a += condW[(jj * 256 + base + rr) * 80 + q] * y[q * 16 + f];
      s_cond[f * 128 + rr] = a;
    }
    __syncthreads();
    const int dj = 1 << jj, maskj = 2 * dj - 1;
    float* ringj = ws + OFF_RINGS + 512 * (dj - 1);
    const u64* pza = zq + ((jj - 1) * 2 + 0) * 256;
    const u64* pzb = zq + ((jj - 1) * 2 + 1) * 256;
    const u64* pxp = xq + (jj - 1) * 256;    // x_{j-1}; jj==1 -> xq_1 from L0
    u64* zout = zq + (jj * 2 + side) * 256;
    u64* xout = xq + jj * 256;               // published by side 0, jj>=2
    const u64* ptap = tq + (jj - 1) * 32 * 256;

    for (int t = 0; t < T_STEPS; ++t) {
      const int want = t + 1;
      if (tid < 256) {
        float xv;
        if (jj == 1) {
          xv = spin_pair(xq + 1 * 256 + tid, want);       // x1 fully formed
        } else {
          float a, b, r3;
          spin3(pza + tid, pzb + tid, pxp + tid, want, a, b, r3);
          xv = fmaxf(a + b + bprev + r3, 0.f);
        }
        s_x[tid] = xv;
        if (side == 0) {
          stc(ringj + (t & maskj) * 256 + tid, xv);       // for tap helper
          if (jj >= 2) stq(xout + tid, xv, want);         // early x publish
        }
      } else if (tid < 384) {
        int l = tid - 256;
        s_tap[l] = spin_pair(ptap + (t & 31) * 256 + base + l, want);
      }
      __syncthreads();
      { int r = tid & 127, s = tid >> 7;
        float acc = 0.f;
#pragma unroll
        for (int i = 0; i < 64; ++i) acc += wp[i] * s_x[64 * s + i];
        s_p[s * 128 + r] = acc; }
      __syncthreads();
      if (tid < 128) {
        int f = t >> 7;
        float hv = s_p[tid] + s_p[128 + tid] + s_p[256 + tid] + s_p[384 + tid]
                 + s_cond[f * 128 + tid] + s_tap[tid];
        s_h[tid] = fmaxf(hv, 0.f);
      }
      __syncthreads();
      { int cc = tid & 255, s2 = tid >> 8;
        float acc = 0.f;
#pragma unroll
        for (int i = 0; i < 64; ++i) acc += wo[i] * s_h[64 * s2 + i];
        s_p[s2 * 256 + cc] = acc; }
      __syncthreads();
      if (side == 0)
        __builtin_amdgcn_fence(__ATOMIC_RELEASE, "agent");  // ring visible before z tag
      if (tid < 256) stq(zout + tid, s_p[tid] + s_p[256 + tid], want);
    }

  } else {
    // ------------------------- tap helpers (j = 1..10) ----------------------
    const int j = role - 21;
    const int dj = 1 << j, maskj = 2 * dj - 1;
    float wq[128];
    { const float* W = WV_past + j * 65536;
      int r = tid & 255, s2 = tid >> 8;
#pragma unroll
      for (int i = 0; i < 128; ++i) wq[i] = W[r * 256 + 128 * s2 + i]; }
    float* ringj = ws + OFF_RINGS + 512 * (dj - 1);
    u64* tapj = tq + (j - 1) * 32 * 256;
    const u64* pza = zq + (j * 2 + 0) * 256;
    const u64* pzb = zq + (j * 2 + 1) * 256;

    for (int t = 0; t < T_STEPS; ++t) {
      // gates: ring(t-dj) visible via z_jA tag (fence-ordered);
      // tap-slot clobber safety: both halves past step t-32.
      int wgA = (t >= dj) ? (t - dj + 1) : (t - 31);
      if (wgA < t - 31) wgA = t - 31;
      int wgB = t - 31;
      if (tid < 256 && (wgA >= 1 || wgB >= 1))
        spin_tag2(pza + tid, pzb + tid, wgA, wgB);
      float tapv = 0.f;
      if (t >= dj) {
        if (tid < 256) s_x[tid] = ldc(ringj + ((t - dj) & maskj) * 256 + tid);
        __syncthreads();
        int r = tid & 255, s2 = tid >> 8;
        float acc = 0.f;
#pragma unroll
        for (int i = 0; i < 128; ++i) acc += wq[i] * s_x[128 * s2 + i];
        s_p[s2 * 256 + r] = acc;
        __syncthreads();
        if (tid < 256) tapv = s_p[tid] + s_p[256 + tid];
      }
      if (tid < 256) stq(tapj + (t & 31) * 256 + tid, tapv, t + 1);
      __syncthreads();
    }
  }
}

extern "C" void kernel_launch(void* const* d_in, const int* in_sizes, int n_in,
                              void* d_out, int out_size, void* d_ws, size_t ws_size,
                              hipStream_t stream) {
  const float* y       = (const float*)d_in[0];
  const float* samples = (const float*)d_in[1];
  const float* emb_raw = (const float*)d_in[2];
  const float* condW   = (const float*)d_in[3];
  const float* WV_past = (const float*)d_in[4];
  const float* WV_pres = (const float*)d_in[5];
  const float* W_o_w   = (const float*)d_in[6];
  const float* W_o_b   = (const float*)d_in[7];
  const float* end_w   = (const float*)d_in[8];
  const float* end_b   = (const float*)d_in[9];
  (void)in_sizes; (void)n_in; (void)out_size; (void)ws_size;
  hipLaunchKernelGGL(fftnet_kernel, dim3(NROLE), dim3(512), 0, stream,
                     y, samples, emb_raw, condW, WV_past, WV_pres,
                     W_o_w, W_o_b, end_w, end_b, (int*)d_out, (float*)d_ws);
}

// Round 7
// 55181.781 us; speedup vs baseline: 1.1651x; 1.0154x over previous
//
#include <hip/hip_runtime.h>
#include <math.h>

// ---------------------------------------------------------------------------
// FastFFTNet autoregressive sampler on MI355X — round 7: R5/R6 tagged-payload
// pipeline with weights FORCED into VGPRs via ext_vector_type (SSA values,
// no alloca -> no scratch). R6 proved float arrays stay in scratch regardless
// of __launch_bounds__ (VGPR_Count=104): SROA can't promote runtime-indexed
// allocas, and per-step scratch re-reads (~128-256 KB/stage) were the
// dominant per-stage cost. Arithmetic order is byte-identical to R5/R6
// (bit-exact proven). Protocol/comms unchanged.
//
// Roles (32 blocks x 512 thr): 0 sampler | 1 L0 | 2..11 A_j (j=role-1)
//   12..21 B_j (j=role-11) | 22..31 helper_j (j=role-21, past taps)
// ---------------------------------------------------------------------------

#define T_STEPS 2048
#define NROLE   32

typedef unsigned long long u64;
typedef float v64f __attribute__((ext_vector_type(64)));

// ws float offsets
#define OFF_EMBT   0           // tanh(emb_raw)           [256][256]
#define OFF_WPET   65536       // WV_present[0] @ emb^T   [class][256]
#define OFF_WVPET  131072      // WV_past[0]    @ emb^T   [class][256]
#define OFF_RINGS  196608      // ring_j (plain f32) at +512*((1<<j)-1), 512<<j floats
#define OFF_TAPQ   1244672     // pairs [10][32][256]
#define OFF_ZQ     1408512     // pairs [11][2][256] (j=1..10 used)
#define OFF_XQ     1419776     // pairs [11][256]    (x_j; j=1 from L0, j>=2 from A_j)
#define WS_FLOATS  1425408

#define FIDX     0             // int index into iflags
#define FBAR(r)  (32 + 32*(r)) // init barriers; poison-safe monotone

// ---- agent-scope primitives (proven coherence class) ----------------------
__device__ __forceinline__ float ldc(const float* p) {
  int v = __hip_atomic_load((const int*)p, __ATOMIC_RELAXED, __HIP_MEMORY_SCOPE_AGENT);
  return __int_as_float(v);
}
__device__ __forceinline__ void stc(float* p, float x) {
  __hip_atomic_store((int*)p, __float_as_int(x), __ATOMIC_RELAXED, __HIP_MEMORY_SCOPE_AGENT);
}
__device__ __forceinline__ u64 ldq(const u64* p) {
  return __hip_atomic_load(p, __ATOMIC_RELAXED, __HIP_MEMORY_SCOPE_AGENT);
}
__device__ __forceinline__ void stq(u64* p, float v, int tag) {
  u64 x = (u64)(unsigned)__float_as_int(v) | ((u64)(unsigned)tag << 32);
  __hip_atomic_store(p, x, __ATOMIC_RELAXED, __HIP_MEMORY_SCOPE_AGENT);
}
__device__ __forceinline__ int ptag(u64 q) { return (int)(q >> 32); }
__device__ __forceinline__ float pval(u64 q) { return __int_as_float((int)(unsigned)q); }

__device__ __forceinline__ float spin_pair(const u64* p, int want) {
  int bud = 1 << 20; u64 q;
  do { q = ldq(p); } while (ptag(q) < want && --bud > 0);
  return pval(q);
}
__device__ __forceinline__ void spin3(const u64* p1, const u64* p2, const u64* p3,
                                      int want, float& v1, float& v2, float& v3) {
  int bud = 1 << 20; u64 q1, q2, q3; bool ok;
  do {
    q1 = ldq(p1); q2 = ldq(p2); q3 = ldq(p3);
    ok = (ptag(q1) >= want) & (ptag(q2) >= want) & (ptag(q3) >= want);
  } while (!ok && --bud > 0);
  v1 = pval(q1); v2 = pval(q2); v3 = pval(q3);
}
__device__ __forceinline__ void spin_tag2(const u64* p1, const u64* p2, int w1, int w2) {
  int bud = 1 << 20; u64 q1, q2; bool ok;
  do {
    q1 = ldq(p1); q2 = ldq(p2);
    ok = (ptag(q1) >= w1) & (ptag(q2) >= w2);
  } while (!ok && --bud > 0);
}
__device__ __forceinline__ void wait1(int* f, int want) {
  int it = 0;
  while (__hip_atomic_load(f, __ATOMIC_RELAXED, __HIP_MEMORY_SCOPE_AGENT) < want) {
    if (++it > (1 << 22)) break;
  }
  (void)__hip_atomic_load(f, __ATOMIC_ACQUIRE, __HIP_MEMORY_SCOPE_AGENT);
}
__device__ __forceinline__ void post(int* f, int v) {
  __hip_atomic_store(f, v, __ATOMIC_RELEASE, __HIP_MEMORY_SCOPE_AGENT);
}

__global__ __launch_bounds__(512, 1)
void fftnet_kernel(const float* __restrict__ y, const float* __restrict__ samples,
                   const float* __restrict__ emb_raw, const float* __restrict__ condW,
                   const float* __restrict__ WV_past, const float* __restrict__ WV_present,
                   const float* __restrict__ W_o_w, const float* __restrict__ W_o_b,
                   const float* __restrict__ end_w, const float* __restrict__ end_b,
                   int* __restrict__ out, float* __restrict__ ws)
{
  const int tid = threadIdx.x;
  const int role = blockIdx.x;
  int* iflags = (int*)(ws + WS_FLOATS);
  u64* zq  = (u64*)(ws + OFF_ZQ);
  u64* xq  = (u64*)(ws + OFF_XQ);
  u64* tq  = (u64*)(ws + OFF_TAPQ);

  __shared__ float s_x[256];
  __shared__ float s_h[256];
  __shared__ float s_p[1024];
  __shared__ float s_cond[16 * 256];
  __shared__ float s_tap[128];
  __shared__ float s_m[320];
  __shared__ unsigned long long s_mask[8];

  // ---- init B: embt = tanh(emb_raw) ---------------------------------------
  for (int i = role * 512 + tid; i < 65536; i += NROLE * 512)
    stc(ws + OFF_EMBT + i, tanhf(emb_raw[i]));
  __syncthreads();
  if (tid == 0) post(iflags + FBAR(role), 1);
  if (tid < NROLE) wait1(iflags + FBAR(tid), 1);
  __syncthreads();

  // ---- init C: WPEt / WVP0Et tables ---------------------------------------
  for (int n = role; n < 512; n += NROLE) {
    const float* wmat = (n < 256) ? WV_present : WV_past;  // layer-0 slice
    int cls = n & 255;
    int c = tid & 255, s2 = tid >> 8;
    float acc = 0.f;
    for (int k = 128 * s2; k < 128 * s2 + 128; ++k)
      acc += wmat[c * 256 + k] * ws[OFF_EMBT + cls * 256 + k];
    s_p[s2 * 256 + c] = acc;
    __syncthreads();
    if (tid < 256)
      stc(ws + ((n < 256) ? OFF_WPET : OFF_WVPET) + cls * 256 + tid, s_p[tid] + s_p[256 + tid]);
    __syncthreads();
  }
  __syncthreads();
  if (tid == 0) post(iflags + FBAR(role), 2);
  if (tid < NROLE) wait1(iflags + FBAR(tid), 2);
  __syncthreads();
  __builtin_amdgcn_fence(__ATOMIC_ACQUIRE, "agent");   // invalidate stale L1
  __syncthreads();

  // =========================================================================
  if (role == 0) {
    // ------------------------- sampler -------------------------------------
    const int c = tid & 255, s2 = tid >> 8;
    v64f we0, we1;                       // end_w row halves — SSA, VGPR-resident
#pragma unroll
    for (int i = 0; i < 64; ++i) we0[i] = end_w[c * 256 + 128 * s2 + i];
#pragma unroll
    for (int i = 0; i < 64; ++i) we1[i] = end_w[c * 256 + 128 * s2 + 64 + i];
    const float eb = end_b[c];
    const float b10 = W_o_b[10 * 256 + c];
    const u64* pza = zq + (10 * 2 + 0) * 256;
    const u64* pzb = zq + (10 * 2 + 1) * 256;
    const u64* pxq = xq + 10 * 256;
    const int lane = tid & 63, w = tid >> 6;
    if (tid == 0)
      __hip_atomic_store(iflags + FIDX, (1 << 8) | 127, __ATOMIC_RELAXED,
                         __HIP_MEMORY_SCOPE_AGENT);

    for (int t = 0; t < T_STEPS; ++t) {
      float u = samples[t];
      if (tid < 256) {
        float a, b, r3;
        spin3(pza + tid, pzb + tid, pxq + tid, t + 1, a, b, r3);
        s_x[tid] = fmaxf(a + b + b10 + r3, 0.f);
      }
      __syncthreads();
      // same association order as R5/R6: single chain i=0..127
      float acc = 0.f;
#pragma unroll
      for (int i = 0; i < 64; ++i) acc += we0[i] * s_x[128 * s2 + i];
#pragma unroll
      for (int i = 0; i < 64; ++i) acc += we1[i] * s_x[128 * s2 + 64 + i];
      s_p[s2 * 256 + c] = acc;
      __syncthreads();
      float logit = 0.f;
      if (tid < 256) logit = s_p[tid] + s_p[256 + tid] + eb;
      float vmax = (tid < 256) ? logit : -3.4e38f;
#pragma unroll
      for (int d = 32; d > 0; d >>= 1) vmax = fmaxf(vmax, __shfl_xor(vmax, d, 64));
      if (lane == 0) s_m[280 + w] = vmax;
      __syncthreads();
      float mx = fmaxf(fmaxf(s_m[280], s_m[281]), fmaxf(s_m[282], s_m[283]));
      float e = (tid < 256) ? expf(logit - mx) : 0.f;
      float vs = e;
#pragma unroll
      for (int d = 32; d > 0; d >>= 1) vs += __shfl_xor(vs, d, 64);
      if (lane == 0) s_m[288 + w] = vs;
      __syncthreads();
      float ssum = s_m[288] + s_m[289] + s_m[290] + s_m[291];
      float p = (tid < 256) ? (e / ssum) : 0.f;
      float v = p;
#pragma unroll
      for (int d = 1; d < 64; d <<= 1) {
        float o = __shfl_up(v, (unsigned)d, 64);
        if (lane >= d) v += o;
      }
      if (tid < 256 && lane == 63) s_m[256 + w] = v;
      __syncthreads();
      float offs = 0.f;
      if (tid < 256) for (int k = 0; k < w; ++k) offs += s_m[256 + k];
      float cum = v + offs;
      unsigned long long msk = __ballot(tid < 256 && (cum > u));
      if (lane == 0) s_mask[w] = msk;
      __syncthreads();
      if (tid == 0) {
        int idx = 0;
        for (int k = 0; k < 4; ++k) {
          unsigned long long m2 = s_mask[k];
          if (m2) { idx = k * 64 + (int)__builtin_ctzll(m2); break; }
        }
        __hip_atomic_store(iflags + FIDX, ((t + 2) << 8) | idx, __ATOMIC_RELAXED,
                           __HIP_MEMORY_SCOPE_AGENT);
        out[t] = idx;
      }
      __syncthreads();
    }

  } else if (role == 1) {
    // ------------------------- L0: idx -> x1 (tagged) -----------------------
    v64f wo00, wo01;
    { int c = tid & 255, s2 = tid >> 8;
#pragma unroll
      for (int i = 0; i < 64; ++i) wo00[i] = W_o_w[c * 256 + 128 * s2 + i];
#pragma unroll
      for (int i = 0; i < 64; ++i) wo01[i] = W_o_w[c * 256 + 128 * s2 + 64 + i]; }
    const float b0 = W_o_b[tid & 255];
    for (int e = tid; e < 4096; e += 512) {
      int f = e >> 8, r = e & 255;
      float a = 0.f;
      for (int q = 0; q < 80; ++q) a += condW[r * 80 + q] * y[q * 16 + f];
      s_cond[f * 256 + r] = a;
    }
    __syncthreads();
    u64* px1 = xq + 1 * 256;
    int pidx = 127;

    for (int t = 0; t < T_STEPS; ++t) {
      float tapv = 0.f;
      if (tid < 256 && t > 0) tapv = ws[OFF_WVPET + pidx * 256 + tid];  // prefetch
      int v, bud = 1 << 20;
      do {
        v = __hip_atomic_load(iflags + FIDX, __ATOMIC_RELAXED, __HIP_MEMORY_SCOPE_AGENT);
      } while (v < ((t + 1) << 8) && --bud > 0);
      const int idx = v & 255;
      if (tid < 256) {
        s_x[tid] = ws[OFF_EMBT + idx * 256 + tid];
        float hv = s_cond[(t >> 7) * 256 + tid] + ws[OFF_WPET + idx * 256 + tid] + tapv;
        s_h[tid] = fmaxf(hv, 0.f);
      }
      __syncthreads();
      { // two 64-chunk accumulators per half — bit-exact (R3/R5-proven)
        int c = tid & 255, s2 = tid >> 8;
        float a0 = 0.f, a1 = 0.f;
#pragma unroll
        for (int i = 0; i < 64; ++i) a0 += wo00[i] * s_h[128 * s2 + i];
#pragma unroll
        for (int i = 0; i < 64; ++i) a1 += wo01[i] * s_h[128 * s2 + 64 + i];
        s_p[s2 * 256 + c] = a0 + a1;
      }
      __syncthreads();
      if (tid < 256)
        stq(px1 + tid, fmaxf(s_p[tid] + s_p[256 + tid] + b0 + s_x[tid], 0.f), t + 1);
      pidx = idx;
    }

  } else if (role <= 21) {
    // ------------------------- layer stages A/B (j = 1..10) -----------------
    const int jj = (role <= 11) ? (role - 1) : (role - 11);
    const int side = (role <= 11) ? 0 : 1;
    const int base = side * 128;
    v64f wpv, wov;
    { const float* W = WV_present + jj * 65536;
      int r = tid & 127, s = tid >> 7;
#pragma unroll
      for (int i = 0; i < 64; ++i) wpv[i] = W[(base + r) * 256 + 64 * s + i]; }
    { const float* W = W_o_w + jj * 65536;
      int c = tid & 255, s2 = tid >> 8;
#pragma unroll
      for (int i = 0; i < 64; ++i) wov[i] = W[c * 256 + base + 64 * s2 + i]; }
    const float bprev = W_o_b[(jj - 1) * 256 + (tid & 255)];
    for (int e = tid; e < 2048; e += 512) {
      int f = e >> 7, rr = e & 127;
      float a = 0.f;
      for (int q = 0; q < 80; ++q) a += condW[(jj * 256 + base + rr) * 80 + q] * y[q * 16 + f];
      s_cond[f * 128 + rr] = a;
    }
    __syncthreads();
    const int dj = 1 << jj, maskj = 2 * dj - 1;
    float* ringj = ws + OFF_RINGS + 512 * (dj - 1);
    const u64* pza = zq + ((jj - 1) * 2 + 0) * 256;
    const u64* pzb = zq + ((jj - 1) * 2 + 1) * 256;
    const u64* pxp = xq + (jj - 1) * 256;    // x_{j-1}; jj==1 -> xq_1 from L0
    u64* zout = zq + (jj * 2 + side) * 256;
    u64* xout = xq + jj * 256;               // published by side 0, jj>=2
    const u64* ptap = tq + (jj - 1) * 32 * 256;

    for (int t = 0; t < T_STEPS; ++t) {
      const int want = t + 1;
      if (tid < 256) {
        float xv;
        if (jj == 1) {
          xv = spin_pair(xq + 1 * 256 + tid, want);       // x1 fully formed
        } else {
          float a, b, r3;
          spin3(pza + tid, pzb + tid, pxp + tid, want, a, b, r3);
          xv = fmaxf(a + b + bprev + r3, 0.f);
        }
        s_x[tid] = xv;
        if (side == 0) {
          stc(ringj + (t & maskj) * 256 + tid, xv);       // for tap helper
          if (jj >= 2) stq(xout + tid, xv, want);         // early x publish
        }
      } else if (tid < 384) {
        int l = tid - 256;
        s_tap[l] = spin_pair(ptap + (t & 31) * 256 + base + l, want);
      }
      __syncthreads();
      { int r = tid & 127, s = tid >> 7;
        float acc = 0.f;
#pragma unroll
        for (int i = 0; i < 64; ++i) acc += wpv[i] * s_x[64 * s + i];
        s_p[s * 128 + r] = acc; }
      __syncthreads();
      if (tid < 128) {
        int f = t >> 7;
        float hv = s_p[tid] + s_p[128 + tid] + s_p[256 + tid] + s_p[384 + tid]
                 + s_cond[f * 128 + tid] + s_tap[tid];
        s_h[tid] = fmaxf(hv, 0.f);
      }
      __syncthreads();
      { int cc = tid & 255, s2 = tid >> 8;
        float acc = 0.f;
#pragma unroll
        for (int i = 0; i < 64; ++i) acc += wov[i] * s_h[64 * s2 + i];
        s_p[s2 * 256 + cc] = acc; }
      __syncthreads();
      if (side == 0)
        __builtin_amdgcn_fence(__ATOMIC_RELEASE, "agent");  // ring visible before z tag
      if (tid < 256) stq(zout + tid, s_p[tid] + s_p[256 + tid], want);
    }

  } else {
    // ------------------------- tap helpers (j = 1..10) ----------------------
    const int j = role - 21;
    const int dj = 1 << j, maskj = 2 * dj - 1;
    v64f wq0, wq1;
    { const float* W = WV_past + j * 65536;
      int r = tid & 255, s2 = tid >> 8;
#pragma unroll
      for (int i = 0; i < 64; ++i) wq0[i] = W[r * 256 + 128 * s2 + i];
#pragma unroll
      for (int i = 0; i < 64; ++i) wq1[i] = W[r * 256 + 128 * s2 + 64 + i]; }
    float* ringj = ws + OFF_RINGS + 512 * (dj - 1);
    u64* tapj = tq + (j - 1) * 32 * 256;
    const u64* pza = zq + (j * 2 + 0) * 256;
    const u64* pzb = zq + (j * 2 + 1) * 256;

    for (int t = 0; t < T_STEPS; ++t) {
      int wgA = (t >= dj) ? (t - dj + 1) : (t - 31);
      if (wgA < t - 31) wgA = t - 31;
      int wgB = t - 31;
      if (tid < 256 && (wgA >= 1 || wgB >= 1))
        spin_tag2(pza + tid, pzb + tid, wgA, wgB);
      float tapv = 0.f;
      if (t >= dj) {
        if (tid < 256) s_x[tid] = ldc(ringj + ((t - dj) & maskj) * 256 + tid);
        __syncthreads();
        int r = tid & 255, s2 = tid >> 8;
        float acc = 0.f;
#pragma unroll
        for (int i = 0; i < 64; ++i) acc += wq0[i] * s_x[128 * s2 + i];
#pragma unroll
        for (int i = 0; i < 64; ++i) acc += wq1[i] * s_x[128 * s2 + 64 + i];
        s_p[s2 * 256 + r] = acc;
        __syncthreads();
        if (tid < 256) tapv = s_p[tid] + s_p[256 + tid];
      }
      if (tid < 256) stq(tapj + (t & 31) * 256 + tid, tapv, t + 1);
      __syncthreads();
    }
  }
}

extern "C" void kernel_launch(void* const* d_in, const int* in_sizes, int n_in,
                              void* d_out, int out_size, void* d_ws, size_t ws_size,
                              hipStream_t stream) {
  const float* y       = (const float*)d_in[0];
  const float* samples = (const float*)d_in[1];
  const float* emb_raw = (const float*)d_in[2];
  const float* condW   = (const float*)d_in[3];
  const float* WV_past = (const float*)d_in[4];
  const float* WV_pres = (const float*)d_in[5];
  const float* W_o_w   = (const float*)d_in[6];
  const float* W_o_b   = (const float*)d_in[7];
  const float* end_w   = (const float*)d_in[8];
  const float* end_b   = (const float*)d_in[9];
  (void)in_sizes; (void)n_in; (void)out_size; (void)ws_size;
  hipLaunchKernelGGL(fftnet_kernel, dim3(NROLE), dim3(512), 0, stream,
                     y, samples, emb_raw, condW, WV_past, WV_pres,
                     W_o_w, W_o_b, end_w, end_b, (int*)d_out, (float*)d_ws);
}